// Round 7
// baseline (122.748 us; speedup 1.0000x reference)
//
#include <hip/hip_runtime.h>
#include <stdint.h>

typedef _Float16 half8  __attribute__((ext_vector_type(8)));
typedef float    floatx2 __attribute__((ext_vector_type(2)));
typedef float    floatx4 __attribute__((ext_vector_type(4)));
typedef uint32_t uint4v  __attribute__((ext_vector_type(4)));

#define KDIM   4096
#define ODIM   11008
#define NG     32
#define K8     512      // qweight dwords per output row
#define KU     512      // x_f16 row length in uint4 units (8 f16 each)
#define KSPLIT 16
#define GPB    2        // groups (128 k) per k-chunk: 256 k per block
#define OBLK   172      // o-blocks of 64 columns: 172*64 = 11008

__global__ void zero_out_kernel(float4* __restrict__ out) {
    out[(size_t)blockIdx.x * 256 + threadIdx.x] = float4{0.f, 0.f, 0.f, 0.f};
}

__device__ __forceinline__ uint32_t pk_f16(float a, float b) {
    return __builtin_bit_cast(uint32_t, __builtin_amdgcn_cvt_pkrtz(a, b));
}

// x fp32 [64][4096] -> f16 packed + slot-reordered into xh; also per-(m,group)
// row sums into xsumT[32][64]. Slot order per 8-k chunk: dword j = (x_j, x_{j+4})
// so that B dequant needs no v_perm. x is fp32-upcast fp16 -> conversion exact.
__global__ __launch_bounds__(256) void cvt_x_kernel(
    const float4* __restrict__ x, uint4v* __restrict__ xh,
    float* __restrict__ xsumT)
{
    const size_t i = (size_t)blockIdx.x * 256 + threadIdx.x;
    const float4 f0 = x[2 * i];       // k0..k0+3
    const float4 f1 = x[2 * i + 1];   // k0+4..k0+7
    xh[i] = uint4v{pk_f16(f0.x, f1.x), pk_f16(f0.y, f1.y),
                   pk_f16(f0.z, f1.z), pk_f16(f0.w, f1.w)};

    // group sum (128 k = 16 consecutive threads, block spans 16 aligned groups)
    float p = f0.x + f0.y + f0.z + f0.w + f1.x + f1.y + f1.z + f1.w;
    p += __shfl_xor(p, 1);
    p += __shfl_xor(p, 2);
    p += __shfl_xor(p, 4);
    p += __shfl_xor(p, 8);
    if ((threadIdx.x & 15) == 0) {
        const size_t k0 = i * 8;
        const int m = (int)(k0 >> 12);        // row
        const int g = (int)(k0 >> 7) & 31;    // group
        xsumT[g * 64 + m] = p;
    }
}

struct GBuf { uint4v a[4]; uint4v u[4]; };   // x frags + qweight (4 subs)

// Block: 256 thr = 4 waves. Wave wv: M-tile wv (16 rows) x 64 o-cols (4 subtiles).
// Grid: OBLK*KSPLIT = 2752 blocks; block covers 256 k, atomic-accumulates.
// B fragment = ((u>>4j)&0x000F000F)|0x64006400 directly (slot pair (n_j,n_{j+4}));
// zero-point handled via s*(1024+z)*rowsum correction.
__global__ __launch_bounds__(256, 4) void w4a16_kernel(
    const uint4v*   __restrict__ xh,     // [64][512] packed f16, reordered
    const uint32_t* __restrict__ qw,     // [11008][512]
    const uint32_t* __restrict__ qz,     // [11008][4]
    const float*    __restrict__ sc,     // [11008][32] (fp32-upcast fp16)
    const float*    __restrict__ xsumT,  // [32][64]
    float*          __restrict__ out)    // [64][11008]
{
    const int t    = threadIdx.x;
    const int wv   = t >> 6;
    const int lane = t & 63;
    const int q    = lane >> 4;
    const int ml   = lane & 15;

    const int ob = blockIdx.x % OBLK;
    const int kb = blockIdx.x / OBLK;
    const int o0 = ob * 64;
    const int g0 = kb * GPB;
    const int m  = wv * 16 + ml;

    const uint4v*   xp  = xh + (size_t)m * KU + (size_t)g0 * 16 + q * 4;
    const uint32_t* qwp = qw + (size_t)(o0 + ml) * K8 + (size_t)g0 * 16 + q * 4;

    // Hoisted per-subtile zero dword (8 groups >= our 2) and scales.
    uint32_t zdw[4];
    floatx2  svec[4];
    #pragma unroll
    for (int sub = 0; sub < 4; ++sub) {
        const int o = o0 + sub * 16 + ml;
        zdw[sub]  = qz[(size_t)o * 4 + (g0 >> 3)];
        svec[sub] = *reinterpret_cast<const floatx2*>(sc + (size_t)o * NG + g0);
    }
    const int zsh0 = (g0 & 7) * 4;    // bit offset of group g0's nibble in zdw

    // row sums for this lane's 4 C rows, per group
    const int mrow = wv * 16 + q * 4;
    floatx4 xsv[GPB];
    #pragma unroll
    for (int g = 0; g < GPB; ++g)
        xsv[g] = *reinterpret_cast<const floatx4*>(xsumT + (g0 + g) * 64 + mrow);

    floatx4 acc[4] = {{0.f,0.f,0.f,0.f},{0.f,0.f,0.f,0.f},
                      {0.f,0.f,0.f,0.f},{0.f,0.f,0.f,0.f}};

    GBuf buf[2];
    auto load_g = [&](int g, GBuf& B) {
        #pragma unroll
        for (int ks = 0; ks < 4; ++ks)
            B.a[ks] = xp[g * 16 + ks];
        #pragma unroll
        for (int sub = 0; sub < 4; ++sub)
            B.u[sub] = *reinterpret_cast<const uint4v*>(
                qwp + (size_t)sub * 16 * K8 + g * 16);
    };

    load_g(0, buf[0]);

    #pragma unroll
    for (int g = 0; g < GPB; ++g) {
        if (g + 1 < GPB) load_g(g + 1, buf[(g + 1) & 1]);
        GBuf& B = buf[g & 1];

        half8 afrag[4];
        #pragma unroll
        for (int ks = 0; ks < 4; ++ks)
            afrag[ks] = __builtin_bit_cast(half8, B.a[ks]);

        #pragma unroll
        for (int sub = 0; sub < 4; ++sub) {
            const uint32_t zn = (zdw[sub] >> (zsh0 + g * 4)) & 0xFu;
            const float    s  = svec[sub][g];
            const float    czs = s * (1024.0f + (float)zn);

            floatx4 tmp = {0.f, 0.f, 0.f, 0.f};
            #pragma unroll
            for (int ks = 0; ks < 4; ++ks) {
                const uint32_t ud = B.u[sub][ks];
                // B dwords directly: halves are exact fp16 (1024 + nibble)
                const uint4v bw = {
                    ( ud         & 0x000F000Fu) | 0x64006400u,
                    ((ud >> 4)   & 0x000F000Fu) | 0x64006400u,
                    ((ud >> 8)   & 0x000F000Fu) | 0x64006400u,
                    ((ud >> 12)  & 0x000F000Fu) | 0x64006400u};
                const half8 b = __builtin_bit_cast(half8, bw);
                tmp = __builtin_amdgcn_mfma_f32_16x16x32_f16(afrag[ks], b, tmp, 0, 0, 0);
            }
            #pragma unroll
            for (int r = 0; r < 4; ++r) {
                acc[sub][r] += s * tmp[r];
                acc[sub][r] -= czs * xsv[g][r];
            }
        }
    }

    // C/D layout: col = lane&15, row = q*4 + reg; accumulate across k-chunks.
    #pragma unroll
    for (int sub = 0; sub < 4; ++sub) {
        float* op = out + (size_t)mrow * ODIM + (o0 + sub * 16 + ml);
        atomicAdd(op,                  acc[sub][0]);
        atomicAdd(op + (size_t)ODIM,   acc[sub][1]);
        atomicAdd(op + 2*(size_t)ODIM, acc[sub][2]);
        atomicAdd(op + 3*(size_t)ODIM, acc[sub][3]);
    }
}

extern "C" void kernel_launch(void* const* d_in, const int* in_sizes, int n_in,
                              void* d_out, int out_size, void* d_ws, size_t ws_size,
                              hipStream_t stream) {
    const float*    x       = (const float*)d_in[0];
    const uint32_t* qweight = (const uint32_t*)d_in[1];
    const uint32_t* qzeros  = (const uint32_t*)d_in[2];
    const float*    scales  = (const float*)d_in[3];
    float* out = (float*)d_out;
    uint4v* xh    = (uint4v*)d_ws;                         // 512 KB
    float*  xsumT = (float*)((char*)d_ws + 512 * 1024);    // 8 KB

    cvt_x_kernel<<<dim3(128), dim3(256), 0, stream>>>((const float4*)x, xh, xsumT);
    zero_out_kernel<<<dim3(688), dim3(256), 0, stream>>>((float4*)out);
    w4a16_kernel<<<dim3(OBLK * KSPLIT), dim3(256), 0, stream>>>(
        xh, qweight, qzeros, scales, xsumT, out);
}

// Round 8
// 100.190 us; speedup vs baseline: 1.2251x; 1.2251x over previous
//
#include <hip/hip_runtime.h>
#include <stdint.h>

typedef _Float16 half8  __attribute__((ext_vector_type(8)));
typedef float    floatx4 __attribute__((ext_vector_type(4)));
typedef uint32_t uint4v  __attribute__((ext_vector_type(4)));

#define KDIM   4096
#define ODIM   11008
#define NG     32
#define K8     512      // qweight dwords per output row
#define KU     512      // x_f16 row length in uint4 units (8 f16 each)
#define KSPLIT 8
#define GPB    4        // groups (128 k) per k-chunk: 512 k per block
#define OBLK   172      // o-blocks of 64 columns
#define PART_ELEMS (64 * ODIM)          // floats per k-partial (704512)
#define LDS_PITCH 20    // dwords per o-row slice: 16 data + 4 pad (80 B)

__device__ __forceinline__ uint32_t pk_f16(float a, float b) {
    return __builtin_bit_cast(uint32_t, __builtin_amdgcn_cvt_pkrtz(a, b));
}

// x fp32 [64][4096] -> f16 packed + slot-reordered (dword j = (x_j, x_{j+4}))
// + per-(m,group) row sums (for zero-point correction). Conversion exact.
__global__ __launch_bounds__(256) void cvt_x_kernel(
    const float4* __restrict__ x, uint4v* __restrict__ xh,
    float* __restrict__ xsumT)
{
    const size_t i = (size_t)blockIdx.x * 256 + threadIdx.x;
    const float4 f0 = x[2 * i];
    const float4 f1 = x[2 * i + 1];
    xh[i] = uint4v{pk_f16(f0.x, f1.x), pk_f16(f0.y, f1.y),
                   pk_f16(f0.z, f1.z), pk_f16(f0.w, f1.w)};

    float p = f0.x + f0.y + f0.z + f0.w + f1.x + f1.y + f1.z + f1.w;
    p += __shfl_xor(p, 1);
    p += __shfl_xor(p, 2);
    p += __shfl_xor(p, 4);
    p += __shfl_xor(p, 8);
    if ((threadIdx.x & 15) == 0) {
        const size_t k0 = i * 8;
        const int m = (int)(k0 >> 12);
        const int g = (int)(k0 >> 7) & 31;
        xsumT[g * 64 + m] = p;
    }
}

// out[i] = sum of KSPLIT partials
__global__ __launch_bounds__(256) void reduce_kernel(
    const float4* __restrict__ part, float4* __restrict__ out)
{
    const size_t i = (size_t)blockIdx.x * 256 + threadIdx.x;   // 176128 float4
    float4 a = part[i];
    #pragma unroll
    for (int kb = 1; kb < KSPLIT; ++kb) {
        const float4 b = part[(size_t)kb * (PART_ELEMS / 4) + i];
        a.x += b.x; a.y += b.y; a.z += b.z; a.w += b.w;
    }
    out[i] = a;
}

// Block: 256 thr = 4 waves. Wave wv: M-tile wv (16 rows) x 64 o-cols (4 subs).
// qweight deduped through LDS: per group, ONE dwordx4/wave stages the block's
// 4-KB slice (lane L -> o-row wv*16+L/4, chunk L&3); consumers ds_read_b128.
// Partials per k-chunk (no atomics); zero-point via rowsum correction.
__global__ __launch_bounds__(256, 4) void w4a16_kernel(
    const uint4v*   __restrict__ xh,     // [64][512] packed f16, reordered
    const uint32_t* __restrict__ qw,     // [11008][512]
    const uint32_t* __restrict__ qz,     // [11008][4]
    const float*    __restrict__ sc,     // [11008][32] (fp32-upcast fp16)
    const float*    __restrict__ xsumT,  // [32][64]
    float*          __restrict__ part)   // [KSPLIT][64][11008]
{
    __shared__ uint32_t qlds[2][64 * LDS_PITCH];   // 2 x 5120 B

    const int t    = threadIdx.x;
    const int wv   = t >> 6;
    const int lane = t & 63;
    const int q    = lane >> 4;
    const int ml   = lane & 15;

    const int ob = blockIdx.x % OBLK;
    const int kb = blockIdx.x / OBLK;
    const int o0 = ob * 64;
    const int g0 = kb * GPB;

    // staging: this lane's global source and LDS dest (dword indices)
    const int srow = wv * 16 + (lane >> 2);        // o-row within block
    const int schk = lane & 3;                     // 16-B chunk within row slice
    const uint32_t* sgp = qw + (size_t)(o0 + srow) * K8 + g0 * 16 + schk * 4;
    const int widx = srow * LDS_PITCH + schk * 4;

    const uint4v* xp = xh + (size_t)(wv * 16 + ml) * KU + (size_t)g0 * 16 + q * 4;

    // prologue: zeros dword + scales + row sums
    uint32_t zdw[4];
    floatx4  svec[4];
    #pragma unroll
    for (int sub = 0; sub < 4; ++sub) {
        const int o = o0 + sub * 16 + ml;
        zdw[sub]  = qz[(size_t)o * 4 + (g0 >> 3)];
        svec[sub] = *reinterpret_cast<const floatx4*>(sc + (size_t)o * NG + g0);
    }
    const int zsh0 = (g0 & 7) * 4;

    const int mrow = wv * 16 + q * 4;
    floatx4 xsv[GPB];
    #pragma unroll
    for (int g = 0; g < GPB; ++g)
        xsv[g] = *reinterpret_cast<const floatx4*>(xsumT + (g0 + g) * 64 + mrow);

    floatx4 acc[4] = {{0.f,0.f,0.f,0.f},{0.f,0.f,0.f,0.f},
                      {0.f,0.f,0.f,0.f},{0.f,0.f,0.f,0.f}};

    uint4v sv = *reinterpret_cast<const uint4v*>(sgp);   // stage g=0

    #pragma unroll
    for (int g = 0; g < GPB; ++g) {
        // write staged slice, then sync
        *reinterpret_cast<uint4v*>(&qlds[g & 1][widx]) = sv;
        __syncthreads();
        // issue next stage AFTER barrier so it overlaps this group's compute
        if (g + 1 < GPB)
            sv = *reinterpret_cast<const uint4v*>(sgp + (g + 1) * 16);

        // x fragments (direct, unique per wave)
        uint4v ax[4];
        #pragma unroll
        for (int ks = 0; ks < 4; ++ks)
            ax[ks] = xp[g * 16 + ks];

        // qweight fragments from LDS
        uint4v qf[4];
        #pragma unroll
        for (int sub = 0; sub < 4; ++sub)
            qf[sub] = *reinterpret_cast<const uint4v*>(
                &qlds[g & 1][(sub * 16 + ml) * LDS_PITCH + q * 4]);

        #pragma unroll
        for (int sub = 0; sub < 4; ++sub) {
            const uint32_t zn  = (zdw[sub] >> (zsh0 + g * 4)) & 0xFu;
            const float    s   = svec[sub][g];
            const float    czs = s * (1024.0f + (float)zn);

            floatx4 tmp = {0.f, 0.f, 0.f, 0.f};
            #pragma unroll
            for (int ks = 0; ks < 4; ++ks) {
                const uint32_t ud = qf[sub][ks];
                const uint4v bw = {
                    ( ud         & 0x000F000Fu) | 0x64006400u,
                    ((ud >> 4)   & 0x000F000Fu) | 0x64006400u,
                    ((ud >> 8)   & 0x000F000Fu) | 0x64006400u,
                    ((ud >> 12)  & 0x000F000Fu) | 0x64006400u};
                const half8 b = __builtin_bit_cast(half8, bw);
                tmp = __builtin_amdgcn_mfma_f32_16x16x32_f16(
                    __builtin_bit_cast(half8, ax[ks]), b, tmp, 0, 0, 0);
            }
            #pragma unroll
            for (int r = 0; r < 4; ++r)
                acc[sub][r] += s * tmp[r] - czs * xsv[g][r];
        }
    }

    // plain coalesced stores to this k-chunk's partial
    float* pb = part + (size_t)kb * PART_ELEMS;
    #pragma unroll
    for (int sub = 0; sub < 4; ++sub) {
        float* op = pb + (size_t)mrow * ODIM + (o0 + sub * 16 + ml);
        op[0]                  = acc[sub][0];
        op[(size_t)ODIM]       = acc[sub][1];
        op[2 * (size_t)ODIM]   = acc[sub][2];
        op[3 * (size_t)ODIM]   = acc[sub][3];
    }
}

extern "C" void kernel_launch(void* const* d_in, const int* in_sizes, int n_in,
                              void* d_out, int out_size, void* d_ws, size_t ws_size,
                              hipStream_t stream) {
    const float*    x       = (const float*)d_in[0];
    const uint32_t* qweight = (const uint32_t*)d_in[1];
    const uint32_t* qzeros  = (const uint32_t*)d_in[2];
    const float*    scales  = (const float*)d_in[3];
    float* out = (float*)d_out;

    uint4v* xh    = (uint4v*)d_ws;                            // 512 KB
    float*  xsumT = (float*)((char*)d_ws + 512 * 1024);       // 8 KB
    float*  part  = (float*)((char*)d_ws + 1024 * 1024);      // 22.5 MB

    cvt_x_kernel<<<dim3(128), dim3(256), 0, stream>>>((const float4*)x, xh, xsumT);
    w4a16_kernel<<<dim3(OBLK * KSPLIT), dim3(256), 0, stream>>>(
        xh, qweight, qzeros, scales, xsumT, part);
    reduce_kernel<<<dim3(688), dim3(256), 0, stream>>>(
        (const float4*)part, (float4*)out);
}